// Round 1
// baseline (3576.891 us; speedup 1.0000x reference)
//
#include <hip/hip_runtime.h>

typedef __bf16 bf16x8 __attribute__((ext_vector_type(8)));
typedef float f32x4 __attribute__((ext_vector_type(4)));
typedef int i32x4 __attribute__((ext_vector_type(4)));

#define B_ 2
#define S_ 2048
#define H_ 2048
#define V_ 32000
#define NSEG_ 16
#define R_ 256
#define TM_ 1024
#define MAIN_ROWS 4096          // B*S
#define MROWS 6144              // B*S + B*TM

__device__ __forceinline__ unsigned short f2bf(float f) {
  union { float f; unsigned u; } v; v.f = f;
  unsigned r = (v.u + 0x7fffu + ((v.u >> 16) & 1u)) >> 16;
  return (unsigned short)r;
}

// ---------------- f32 -> bf16 convert (vectorized) ----------------
__global__ void f32_to_bf16_k(const float* __restrict__ in,
                              unsigned short* __restrict__ out, int n4) {
  int i = blockIdx.x * 256 + threadIdx.x;
  if (i < n4) {
    float4 v = ((const float4*)in)[i];
    ushort4 o;
    o.x = f2bf(v.x); o.y = f2bf(v.y); o.z = f2bf(v.z); o.w = f2bf(v.w);
    ((ushort4*)out)[i] = o;
  }
}

// ---------------- adapter: inter = x @ B^T ----------------
// block = (b*TM + t); 256 threads, thread r computes inter[b,t,r]
__global__ void adapter1_k(const float* __restrict__ lhs, const int* __restrict__ starts,
                           const float* __restrict__ Bm, float* __restrict__ inter) {
  int blk = blockIdx.x;
  int b = blk >> 10, t = blk & 1023;
  int seg = t >> 6;
  int pos = starts[b] + t;
  __shared__ __align__(16) float xs[H_];
  const float* xrow = lhs + ((size_t)b * S_ + pos) * H_;
  for (int i = threadIdx.x; i < H_ / 4; i += 256)
    ((float4*)xs)[i] = ((const float4*)xrow)[i];
  __syncthreads();
  int r = threadIdx.x;
  const float* brow = Bm + ((size_t)seg * R_ + r) * H_;
  float acc = 0.f;
  for (int h = 0; h < H_; h += 4) {
    float4 bv = *(const float4*)(brow + h);
    acc += xs[h] * bv.x + xs[h + 1] * bv.y + xs[h + 2] * bv.z + xs[h + 3] * bv.w;
  }
  inter[(size_t)blk * R_ + r] = acc;
}

// ---------------- adapter: trans = inter @ A^T + bias -> bf16 rows of X ----------------
__global__ void adapter2_k(const float* __restrict__ inter, const float* __restrict__ Am,
                           const float* __restrict__ bias, unsigned short* __restrict__ Xbf) {
  int blk = blockIdx.x;
  int t = blk & 1023;
  int seg = t >> 6;
  __shared__ __align__(16) float is[R_];
  is[threadIdx.x] = inter[(size_t)blk * R_ + threadIdx.x];
  __syncthreads();
  for (int j = 0; j < H_ / 256; ++j) {
    int h = threadIdx.x + j * 256;
    const float* arow = Am + ((size_t)seg * H_ + h) * R_;
    float acc = bias[seg * H_ + h];
    for (int r = 0; r < R_; r += 4) {
      float4 av = *(const float4*)(arow + r);
      acc += is[r] * av.x + is[r + 1] * av.y + is[r + 2] * av.z + is[r + 3] * av.w;
    }
    Xbf[((size_t)(MAIN_ROWS + blk)) * H_ + h] = f2bf(acc);
  }
}

// ---------------- fused CE GEMM: rowsum[m] += sum_n exp(X[m]·W[n]) ----------------
#define BM 128
#define BN 128
#define BK 64
#define LDK 72   // padded row (144 B): 2-way bank aliasing only (free)

__global__ __launch_bounds__(256)
void ce_gemm_k(const unsigned short* __restrict__ X, const unsigned short* __restrict__ Wb,
               float* __restrict__ rowsum) {
  __shared__ __align__(16) unsigned short At[BM * LDK];
  __shared__ __align__(16) unsigned short Bt[BN * LDK];
  const int n0 = blockIdx.x * BN;
  const int m0 = blockIdx.y * BM;
  const int tid = threadIdx.x;
  const int wave = tid >> 6, lane = tid & 63;
  const int quad = lane >> 4, l16 = lane & 15;
  const int wrow = (wave >> 1) * 64, wcol = (wave & 1) * 64;

  f32x4 acc[4][4];
  for (int i = 0; i < 4; ++i)
    for (int j = 0; j < 4; ++j)
      acc[i][j] = (f32x4){0.f, 0.f, 0.f, 0.f};

  for (int k0 = 0; k0 < H_; k0 += BK) {
    // stage A and B tiles: 128 rows x 64 bf16 each; 16B chunks, 8 chunks/row
    for (int i = 0; i < 4; ++i) {
      int c = tid + i * 256;
      int row = c >> 3, p = c & 7;
      *(i32x4*)(&At[row * LDK + p * 8]) =
          *(const i32x4*)(&X[(size_t)(m0 + row) * H_ + k0 + p * 8]);
      *(i32x4*)(&Bt[row * LDK + p * 8]) =
          *(const i32x4*)(&Wb[(size_t)(n0 + row) * H_ + k0 + p * 8]);
    }
    __syncthreads();
    for (int kk = 0; kk < BK; kk += 32) {
      bf16x8 af[4], bfr[4];
      for (int rt = 0; rt < 4; ++rt)
        af[rt] = __builtin_bit_cast(bf16x8,
            *(const i32x4*)(&At[(wrow + rt * 16 + l16) * LDK + kk + quad * 8]));
      for (int ct = 0; ct < 4; ++ct)
        bfr[ct] = __builtin_bit_cast(bf16x8,
            *(const i32x4*)(&Bt[(wcol + ct * 16 + l16) * LDK + kk + quad * 8]));
      for (int rt = 0; rt < 4; ++rt)
        for (int ct = 0; ct < 4; ++ct)
          acc[rt][ct] = __builtin_amdgcn_mfma_f32_16x16x32_bf16(
              af[rt], bfr[ct], acc[rt][ct], 0, 0, 0);
    }
    __syncthreads();
  }

  // epilogue: per-row partial sum of exp over this block's 128 cols
  for (int rt = 0; rt < 4; ++rt) {
    float s[4] = {0.f, 0.f, 0.f, 0.f};
    for (int ct = 0; ct < 4; ++ct)
      for (int r = 0; r < 4; ++r)
        s[r] += __expf(acc[rt][ct][r]);
    for (int m = 1; m < 16; m <<= 1)
      for (int r = 0; r < 4; ++r)
        s[r] += __shfl_xor(s[r], m, 64);
    if (l16 == 0) {
      for (int r = 0; r < 4; ++r) {
        int grow = m0 + wrow + rt * 16 + quad * 4 + r;
        atomicAdd(&rowsum[grow], s[r]);
      }
    }
  }
}

// ---------------- target logit per token row ----------------
__global__ void tlogit_k(const unsigned short* __restrict__ Xbf,
                         const unsigned short* __restrict__ Wbf,
                         const int* __restrict__ input_ids,
                         const int* __restrict__ mlabels,
                         float* __restrict__ tlog) {
  int i = blockIdx.x;
  int label;
  if (i < MAIN_ROWS) {
    int b = i >> 11, s = i & 2047;
    label = (s < S_ - 1) ? input_ids[b * S_ + s + 1] : 0;
  } else {
    int j = i - MAIN_ROWS;
    int b = j >> 10, t = j & 1023;
    label = mlabels[b * TM_ + t];
  }
  const unsigned short* x = Xbf + (size_t)i * H_;
  const unsigned short* w = Wbf + (size_t)label * H_;
  int tid = threadIdx.x;
  i32x4 xv = *(const i32x4*)(x + tid * 8);
  i32x4 wv = *(const i32x4*)(w + tid * 8);
  float acc = 0.f;
  for (int q = 0; q < 4; ++q) {
    unsigned xu = (unsigned)xv[q], wu = (unsigned)wv[q];
    float x0 = __uint_as_float(xu << 16), x1 = __uint_as_float(xu & 0xffff0000u);
    float w0 = __uint_as_float(wu << 16), w1 = __uint_as_float(wu & 0xffff0000u);
    acc += x0 * w0 + x1 * w1;
  }
  for (int m = 1; m < 64; m <<= 1) acc += __shfl_xor(acc, m, 64);
  __shared__ float red[4];
  if ((tid & 63) == 0) red[tid >> 6] = acc;
  __syncthreads();
  if (tid == 0) tlog[i] = red[0] + red[1] + red[2] + red[3];
}

// ---------------- final masked means ----------------
__global__ void finalize_k(const float* __restrict__ rowsum, const float* __restrict__ tlog,
                           const int* __restrict__ attn, const int* __restrict__ starts,
                           const int* __restrict__ ends, const int* __restrict__ mmask,
                           float* __restrict__ out) {
  int tid = threadIdx.x;
  __shared__ int tmp[8];
  __shared__ float red[24];
  int s0 = 0, s1 = 0;
  for (int s = tid; s < S_; s += 256) { s0 += attn[s]; s1 += attn[S_ + s]; }
  for (int m = 1; m < 64; m <<= 1) { s0 += __shfl_xor(s0, m, 64); s1 += __shfl_xor(s1, m, 64); }
  if ((tid & 63) == 0) { tmp[(tid >> 6) * 2] = s0; tmp[(tid >> 6) * 2 + 1] = s1; }
  __syncthreads();
  int rl[2];
  rl[0] = tmp[0] + tmp[2] + tmp[4] + tmp[6];
  rl[1] = tmp[1] + tmp[3] + tmp[5] + tmp[7];

  float st_s = 0.f, st_c = 0.f, fa_s = 0.f, fa_c = 0.f, m_s = 0.f, m_c = 0.f;
  for (int i = tid; i < MAIN_ROWS; i += 256) {
    int b = i >> 11, s = i & 2047;
    if (s < S_ - 1) {
      float nll = logf(rowsum[i]) - tlog[i];
      bool stm = (s >= starts[b] - 1) && (s <= ends[b] - 1);
      bool fam = (s >= ends[b]) && (s < rl[b] - 1);
      if (stm) { st_s += nll; st_c += 1.f; }
      if (fam) { fa_s += nll; fa_c += 1.f; }
    }
  }
  for (int i = tid; i < B_ * TM_; i += 256) {
    int row = MAIN_ROWS + i;
    float nll = logf(rowsum[row]) - tlog[row];
    float m = (float)mmask[i];
    m_s += nll * m; m_c += m;
  }
  float vals[6] = {st_s, st_c, fa_s, fa_c, m_s, m_c};
  for (int m = 1; m < 64; m <<= 1)
    for (int q = 0; q < 6; ++q) vals[q] += __shfl_xor(vals[q], m, 64);
  if ((tid & 63) == 0)
    for (int q = 0; q < 6; ++q) red[(tid >> 6) * 6 + q] = vals[q];
  __syncthreads();
  if (tid == 0) {
    float stS = red[0] + red[6] + red[12] + red[18];
    float stC = red[1] + red[7] + red[13] + red[19];
    float faS = red[2] + red[8] + red[14] + red[20];
    float faC = red[3] + red[9] + red[15] + red[21];
    float mS  = red[4] + red[10] + red[16] + red[22];
    float mC  = red[5] + red[11] + red[17] + red[23];
    float st = stS / fmaxf(stC, 1.f);
    float fa = faS / fmaxf(faC, 1.f);
    float ml = mS / fmaxf(mC, 1.f);
    out[0] = 0.5f * ml + 0.5f * st + 0.4f * fa;
    out[1] = ml;
    out[2] = st;
    out[3] = fa;
  }
}

extern "C" void kernel_launch(void* const* d_in, const int* in_sizes, int n_in,
                              void* d_out, int out_size, void* d_ws, size_t ws_size,
                              hipStream_t stream) {
  (void)in_sizes; (void)n_in; (void)out_size; (void)ws_size;
  const float* lhs      = (const float*)d_in[0];
  const int* input_ids  = (const int*)d_in[1];
  const int* attn       = (const int*)d_in[2];
  const int* starts     = (const int*)d_in[3];
  const int* ends       = (const int*)d_in[4];
  const int* mlabels    = (const int*)d_in[5];
  const int* mmask      = (const int*)d_in[6];
  // d_in[7] math_lengths: unused by reference math
  const float* Am       = (const float*)d_in[8];
  const float* Bm       = (const float*)d_in[9];
  const float* bias     = (const float*)d_in[10];
  const float* Wf       = (const float*)d_in[11];
  float* out = (float*)d_out;

  char* ws = (char*)d_ws;
  unsigned short* Wbf = (unsigned short*)ws;                  // 131,072,000 B
  unsigned short* Xbf = (unsigned short*)(ws + 131072000);    //  25,165,824 B
  float* inter        = (float*)(ws + 156237824);             //   2,097,152 B
  float* rowsum       = (float*)(ws + 158334976);             //      24,576 B
  float* tlog         = (float*)(ws + 158359552);             //      24,576 B

  hipMemsetAsync(rowsum, 0, MROWS * sizeof(float), stream);
  f32_to_bf16_k<<<(V_ * H_ / 4 + 255) / 256, 256, 0, stream>>>(Wf, Wbf, V_ * H_ / 4);
  f32_to_bf16_k<<<(MAIN_ROWS * H_ / 4 + 255) / 256, 256, 0, stream>>>(lhs, Xbf, MAIN_ROWS * H_ / 4);
  adapter1_k<<<B_ * TM_, 256, 0, stream>>>(lhs, starts, Bm, inter);
  adapter2_k<<<B_ * TM_, 256, 0, stream>>>(inter, Am, bias, Xbf);
  ce_gemm_k<<<dim3(V_ / BN, MROWS / BM), 256, 0, stream>>>(Xbf, Wbf, rowsum);
  tlogit_k<<<MROWS, 256, 0, stream>>>(Xbf, Wbf, input_ids, mlabels, tlog);
  finalize_k<<<1, 256, 0, stream>>>(rowsum, tlog, attn, starts, ends, mmask, out);
}

// Round 2
// 1860.842 us; speedup vs baseline: 1.9222x; 1.9222x over previous
//
#include <hip/hip_runtime.h>

typedef __bf16 bf16x8 __attribute__((ext_vector_type(8)));
typedef float f32x4 __attribute__((ext_vector_type(4)));
typedef int i32x4 __attribute__((ext_vector_type(4)));

#define B_ 2
#define S_ 2048
#define H_ 2048
#define V_ 32000
#define NSEG_ 16
#define R_ 256
#define TM_ 1024
#define MAIN_ROWS 4096          // B*S
#define MROWS 6144              // B*S + B*TM

__device__ __forceinline__ unsigned short f2bf(float f) {
  union { float f; unsigned u; } v; v.f = f;
  unsigned r = (v.u + 0x7fffu + ((v.u >> 16) & 1u)) >> 16;
  return (unsigned short)r;
}

__device__ __forceinline__ i32x4 pack8(const float* __restrict__ src) {
  float4 v0 = *(const float4*)src;
  float4 v1 = *(const float4*)(src + 4);
  union { unsigned short u[8]; i32x4 v; } o;
  o.u[0] = f2bf(v0.x); o.u[1] = f2bf(v0.y); o.u[2] = f2bf(v0.z); o.u[3] = f2bf(v0.w);
  o.u[4] = f2bf(v1.x); o.u[5] = f2bf(v1.y); o.u[6] = f2bf(v1.z); o.u[7] = f2bf(v1.w);
  return o.v;
}

// ---------------- f32 -> bf16 convert (vectorized) ----------------
__global__ void f32_to_bf16_k(const float* __restrict__ in,
                              unsigned short* __restrict__ out, int n4) {
  int i = blockIdx.x * 256 + threadIdx.x;
  if (i < n4) {
    float4 v = ((const float4*)in)[i];
    ushort4 o;
    o.x = f2bf(v.x); o.y = f2bf(v.y); o.z = f2bf(v.z); o.w = f2bf(v.w);
    ((ushort4*)out)[i] = o;
  }
}

// ---------------- adapter stage 1: inter = x @ Bm^T  (grouped MFMA GEMM) ----------------
// grid = 32 groups (b*16+seg). M=64 tokens, N=256 (r), K=2048(h). Convert-in-staging.
__global__ __launch_bounds__(256)
void adapter1_k(const float* __restrict__ lhs, const int* __restrict__ starts,
                const float* __restrict__ Bm, unsigned short* __restrict__ interb) {
  const int g = blockIdx.x;
  const int b = g >> 4, seg = g & 15;
  __shared__ __align__(16) unsigned short At[64 * 72];
  __shared__ __align__(16) unsigned short Bt[256 * 72];
  const int tid = threadIdx.x;
  const int wave = tid >> 6, lane = tid & 63;
  const int quad = lane >> 4, l16 = lane & 15;
  const int start = starts[b];

  f32x4 acc[4][4];
  for (int i = 0; i < 4; ++i)
    for (int j = 0; j < 4; ++j)
      acc[i][j] = (f32x4){0.f, 0.f, 0.f, 0.f};

  for (int k0 = 0; k0 < H_; k0 += 64) {
    for (int i = 0; i < 2; ++i) {
      int c = tid + i * 256;
      int row = c >> 3, p = c & 7;               // token row 0..63
      int t = seg * 64 + row;
      const float* src = lhs + ((size_t)b * S_ + start + t) * H_ + k0 + p * 8;
      *(i32x4*)(&At[row * 72 + p * 8]) = pack8(src);
    }
    for (int i = 0; i < 8; ++i) {
      int c = tid + i * 256;
      int row = c >> 3, p = c & 7;               // r row 0..255
      const float* src = Bm + ((size_t)seg * R_ + row) * H_ + k0 + p * 8;
      *(i32x4*)(&Bt[row * 72 + p * 8]) = pack8(src);
    }
    __syncthreads();
    for (int kk = 0; kk < 64; kk += 32) {
      bf16x8 af[4], bfr[4];
      for (int rt = 0; rt < 4; ++rt)
        af[rt] = __builtin_bit_cast(bf16x8,
            *(const i32x4*)(&At[(rt * 16 + l16) * 72 + kk + quad * 8]));
      for (int ct = 0; ct < 4; ++ct)
        bfr[ct] = __builtin_bit_cast(bf16x8,
            *(const i32x4*)(&Bt[(wave * 64 + ct * 16 + l16) * 72 + kk + quad * 8]));
      for (int rt = 0; rt < 4; ++rt)
        for (int ct = 0; ct < 4; ++ct)
          acc[rt][ct] = __builtin_amdgcn_mfma_f32_16x16x32_bf16(
              af[rt], bfr[ct], acc[rt][ct], 0, 0, 0);
    }
    __syncthreads();
  }
  for (int rt = 0; rt < 4; ++rt)
    for (int ct = 0; ct < 4; ++ct)
      for (int r = 0; r < 4; ++r) {
        int m = rt * 16 + quad * 4 + r;          // token
        int n = wave * 64 + ct * 16 + l16;       // r index
        interb[((size_t)g * 64 + m) * R_ + n] = f2bf(acc[rt][ct][r]);
      }
}

// ---------------- adapter stage 2: trans = inter @ Am^T + bias -> Xbf ----------------
// grid = 32 groups x 8 h-tiles. M=64 tokens, N=256 h, K=256 r.
__global__ __launch_bounds__(256)
void adapter2_k(const unsigned short* __restrict__ interb, const float* __restrict__ Am,
                const float* __restrict__ bias, unsigned short* __restrict__ Xbf) {
  const int g = blockIdx.x >> 3;
  const int nt = blockIdx.x & 7;
  const int seg = g & 15;
  __shared__ __align__(16) unsigned short At[64 * 72];
  __shared__ __align__(16) unsigned short Bt[256 * 72];
  const int tid = threadIdx.x;
  const int wave = tid >> 6, lane = tid & 63;
  const int quad = lane >> 4, l16 = lane & 15;

  f32x4 acc[4][4];
  for (int i = 0; i < 4; ++i)
    for (int j = 0; j < 4; ++j)
      acc[i][j] = (f32x4){0.f, 0.f, 0.f, 0.f};

  for (int k0 = 0; k0 < R_; k0 += 64) {
    for (int i = 0; i < 2; ++i) {
      int c = tid + i * 256;
      int row = c >> 3, p = c & 7;               // token row
      *(i32x4*)(&At[row * 72 + p * 8]) =
          *(const i32x4*)(interb + ((size_t)g * 64 + row) * R_ + k0 + p * 8);
    }
    for (int i = 0; i < 8; ++i) {
      int c = tid + i * 256;
      int row = c >> 3, p = c & 7;               // h row within tile
      const float* src = Am + ((size_t)seg * H_ + nt * 256 + row) * R_ + k0 + p * 8;
      *(i32x4*)(&Bt[row * 72 + p * 8]) = pack8(src);
    }
    __syncthreads();
    for (int kk = 0; kk < 64; kk += 32) {
      bf16x8 af[4], bfr[4];
      for (int rt = 0; rt < 4; ++rt)
        af[rt] = __builtin_bit_cast(bf16x8,
            *(const i32x4*)(&At[(rt * 16 + l16) * 72 + kk + quad * 8]));
      for (int ct = 0; ct < 4; ++ct)
        bfr[ct] = __builtin_bit_cast(bf16x8,
            *(const i32x4*)(&Bt[(wave * 64 + ct * 16 + l16) * 72 + kk + quad * 8]));
      for (int rt = 0; rt < 4; ++rt)
        for (int ct = 0; ct < 4; ++ct)
          acc[rt][ct] = __builtin_amdgcn_mfma_f32_16x16x32_bf16(
              af[rt], bfr[ct], acc[rt][ct], 0, 0, 0);
    }
    __syncthreads();
  }
  for (int rt = 0; rt < 4; ++rt)
    for (int ct = 0; ct < 4; ++ct)
      for (int r = 0; r < 4; ++r) {
        int m = rt * 16 + quad * 4 + r;          // token
        int h = nt * 256 + wave * 64 + ct * 16 + l16;
        float v = acc[rt][ct][r] + bias[seg * H_ + h];
        Xbf[((size_t)(MAIN_ROWS + g * 64 + m)) * H_ + h] = f2bf(v);
      }
}

// ---------------- fused CE GEMM: rowsum[m] += sum_n exp(X[m]·W[n]) ----------------
// m97 structure: global_load_lds width=16 staging, XOR-swizzled 16B chunks in LDS.
#define BM 128
#define BN 128
#define BK 64

__global__ __launch_bounds__(256)
void ce_gemm_k(const unsigned short* __restrict__ X, const unsigned short* __restrict__ Wb,
               float* __restrict__ rowsum) {
  __shared__ __align__(16) unsigned short At[BM * BK];
  __shared__ __align__(16) unsigned short Bt[BN * BK];
  const int n0 = blockIdx.x * BN;
  const int m0 = blockIdx.y * BM;
  const int tid = threadIdx.x;
  const int wave = tid >> 6, lane = tid & 63;
  const int quad = lane >> 4, l16 = lane & 15;
  const int wrow = (wave >> 1) * 64, wcol = (wave & 1) * 64;

  // staging lane map: each DMA issue covers 8 rows x 8 chunks of 16B.
  // physical chunk (lane&7) holds logical chunk clog = (lane&7) ^ (row&7).
  const int rsub = lane >> 3;                    // row within 8-row group
  const int clog = (lane & 7) ^ rsub;
  const unsigned short* ag = X + (size_t)(m0 + 32 * wave + rsub) * H_ + clog * 8;
  const unsigned short* bg = Wb + (size_t)(n0 + 32 * wave + rsub) * H_ + clog * 8;
  unsigned short* al = &At[(32 * wave) * BK];
  unsigned short* bl = &Bt[(32 * wave) * BK];

  f32x4 acc[4][4];
  for (int i = 0; i < 4; ++i)
    for (int j = 0; j < 4; ++j)
      acc[i][j] = (f32x4){0.f, 0.f, 0.f, 0.f};

  for (int k0 = 0; k0 < H_; k0 += BK) {
    #pragma unroll
    for (int j = 0; j < 4; ++j) {
      __builtin_amdgcn_global_load_lds(
          (const __attribute__((address_space(1))) void*)(ag + (size_t)(8 * j) * H_ + k0),
          (__attribute__((address_space(3))) void*)(al + 8 * j * BK), 16, 0, 0);
      __builtin_amdgcn_global_load_lds(
          (const __attribute__((address_space(1))) void*)(bg + (size_t)(8 * j) * H_ + k0),
          (__attribute__((address_space(3))) void*)(bl + 8 * j * BK), 16, 0, 0);
    }
    __syncthreads();
    #pragma unroll
    for (int kk = 0; kk < BK; kk += 32) {
      const int p = ((kk >> 3) + quad) ^ (l16 & 7);   // de-swizzle
      bf16x8 af[4], bfr[4];
      #pragma unroll
      for (int rt = 0; rt < 4; ++rt)
        af[rt] = __builtin_bit_cast(bf16x8,
            *(const i32x4*)(&At[(wrow + rt * 16 + l16) * BK + p * 8]));
      #pragma unroll
      for (int ct = 0; ct < 4; ++ct)
        bfr[ct] = __builtin_bit_cast(bf16x8,
            *(const i32x4*)(&Bt[(wcol + ct * 16 + l16) * BK + p * 8]));
      #pragma unroll
      for (int rt = 0; rt < 4; ++rt)
        #pragma unroll
        for (int ct = 0; ct < 4; ++ct)
          acc[rt][ct] = __builtin_amdgcn_mfma_f32_16x16x32_bf16(
              af[rt], bfr[ct], acc[rt][ct], 0, 0, 0);
    }
    __syncthreads();
  }

  // epilogue: per-row partial sum of exp over this block's 128 cols
  for (int rt = 0; rt < 4; ++rt) {
    float s[4] = {0.f, 0.f, 0.f, 0.f};
    for (int ct = 0; ct < 4; ++ct)
      for (int r = 0; r < 4; ++r)
        s[r] += __expf(acc[rt][ct][r]);
    for (int m = 1; m < 16; m <<= 1)
      for (int r = 0; r < 4; ++r)
        s[r] += __shfl_xor(s[r], m, 64);
    if (l16 == 0) {
      for (int r = 0; r < 4; ++r) {
        int grow = m0 + wrow + rt * 16 + quad * 4 + r;
        atomicAdd(&rowsum[grow], s[r]);
      }
    }
  }
}

// ---------------- target logit per token row ----------------
__global__ void tlogit_k(const unsigned short* __restrict__ Xbf,
                         const unsigned short* __restrict__ Wbf,
                         const int* __restrict__ input_ids,
                         const int* __restrict__ mlabels,
                         float* __restrict__ tlog) {
  int i = blockIdx.x;
  int label;
  if (i < MAIN_ROWS) {
    int b = i >> 11, s = i & 2047;
    label = (s < S_ - 1) ? input_ids[b * S_ + s + 1] : 0;
  } else {
    int j = i - MAIN_ROWS;
    int b = j >> 10, t = j & 1023;
    label = mlabels[b * TM_ + t];
  }
  const unsigned short* x = Xbf + (size_t)i * H_;
  const unsigned short* w = Wbf + (size_t)label * H_;
  int tid = threadIdx.x;
  i32x4 xv = *(const i32x4*)(x + tid * 8);
  i32x4 wv = *(const i32x4*)(w + tid * 8);
  float acc = 0.f;
  for (int q = 0; q < 4; ++q) {
    unsigned xu = (unsigned)xv[q], wu = (unsigned)wv[q];
    float x0 = __uint_as_float(xu << 16), x1 = __uint_as_float(xu & 0xffff0000u);
    float w0 = __uint_as_float(wu << 16), w1 = __uint_as_float(wu & 0xffff0000u);
    acc += x0 * w0 + x1 * w1;
  }
  for (int m = 1; m < 64; m <<= 1) acc += __shfl_xor(acc, m, 64);
  __shared__ float red[4];
  if ((tid & 63) == 0) red[tid >> 6] = acc;
  __syncthreads();
  if (tid == 0) tlog[i] = red[0] + red[1] + red[2] + red[3];
}

// ---------------- final masked means ----------------
__global__ void finalize_k(const float* __restrict__ rowsum, const float* __restrict__ tlog,
                           const int* __restrict__ attn, const int* __restrict__ starts,
                           const int* __restrict__ ends, const int* __restrict__ mmask,
                           float* __restrict__ out) {
  int tid = threadIdx.x;
  __shared__ int tmp[8];
  __shared__ float red[24];
  int s0 = 0, s1 = 0;
  for (int s = tid; s < S_; s += 256) { s0 += attn[s]; s1 += attn[S_ + s]; }
  for (int m = 1; m < 64; m <<= 1) { s0 += __shfl_xor(s0, m, 64); s1 += __shfl_xor(s1, m, 64); }
  if ((tid & 63) == 0) { tmp[(tid >> 6) * 2] = s0; tmp[(tid >> 6) * 2 + 1] = s1; }
  __syncthreads();
  int rl[2];
  rl[0] = tmp[0] + tmp[2] + tmp[4] + tmp[6];
  rl[1] = tmp[1] + tmp[3] + tmp[5] + tmp[7];

  float st_s = 0.f, st_c = 0.f, fa_s = 0.f, fa_c = 0.f, m_s = 0.f, m_c = 0.f;
  for (int i = tid; i < MAIN_ROWS; i += 256) {
    int b = i >> 11, s = i & 2047;
    if (s < S_ - 1) {
      float nll = logf(rowsum[i]) - tlog[i];
      bool stm = (s >= starts[b] - 1) && (s <= ends[b] - 1);
      bool fam = (s >= ends[b]) && (s < rl[b] - 1);
      if (stm) { st_s += nll; st_c += 1.f; }
      if (fam) { fa_s += nll; fa_c += 1.f; }
    }
  }
  for (int i = tid; i < B_ * TM_; i += 256) {
    int row = MAIN_ROWS + i;
    float nll = logf(rowsum[row]) - tlog[row];
    float m = (float)mmask[i];
    m_s += nll * m; m_c += m;
  }
  float vals[6] = {st_s, st_c, fa_s, fa_c, m_s, m_c};
  for (int m = 1; m < 64; m <<= 1)
    for (int q = 0; q < 6; ++q) vals[q] += __shfl_xor(vals[q], m, 64);
  if ((tid & 63) == 0)
    for (int q = 0; q < 6; ++q) red[(tid >> 6) * 6 + q] = vals[q];
  __syncthreads();
  if (tid == 0) {
    float stS = red[0] + red[6] + red[12] + red[18];
    float stC = red[1] + red[7] + red[13] + red[19];
    float faS = red[2] + red[8] + red[14] + red[20];
    float faC = red[3] + red[9] + red[15] + red[21];
    float mS  = red[4] + red[10] + red[16] + red[22];
    float mC  = red[5] + red[11] + red[17] + red[23];
    float st = stS / fmaxf(stC, 1.f);
    float fa = faS / fmaxf(faC, 1.f);
    float ml = mS / fmaxf(mC, 1.f);
    out[0] = 0.5f * ml + 0.5f * st + 0.4f * fa;
    out[1] = ml;
    out[2] = st;
    out[3] = fa;
  }
}

extern "C" void kernel_launch(void* const* d_in, const int* in_sizes, int n_in,
                              void* d_out, int out_size, void* d_ws, size_t ws_size,
                              hipStream_t stream) {
  (void)in_sizes; (void)n_in; (void)out_size; (void)ws_size;
  const float* lhs      = (const float*)d_in[0];
  const int* input_ids  = (const int*)d_in[1];
  const int* attn       = (const int*)d_in[2];
  const int* starts     = (const int*)d_in[3];
  const int* ends       = (const int*)d_in[4];
  const int* mlabels    = (const int*)d_in[5];
  const int* mmask      = (const int*)d_in[6];
  // d_in[7] math_lengths: unused by reference math
  const float* Am       = (const float*)d_in[8];
  const float* Bm       = (const float*)d_in[9];
  const float* bias     = (const float*)d_in[10];
  const float* Wf       = (const float*)d_in[11];
  float* out = (float*)d_out;

  char* ws = (char*)d_ws;
  unsigned short* Wbf   = (unsigned short*)ws;                  // 131,072,000 B
  unsigned short* Xbf   = (unsigned short*)(ws + 131072000);    //  25,165,824 B
  unsigned short* interb= (unsigned short*)(ws + 156237824);    //   1,048,576 B
  float* rowsum         = (float*)(ws + 157286400);             //      24,576 B
  float* tlog           = (float*)(ws + 157310976);             //      24,576 B

  hipMemsetAsync(rowsum, 0, MROWS * sizeof(float), stream);
  f32_to_bf16_k<<<(V_ * H_ / 4 + 255) / 256, 256, 0, stream>>>(Wf, Wbf, V_ * H_ / 4);
  f32_to_bf16_k<<<(MAIN_ROWS * H_ / 4 + 255) / 256, 256, 0, stream>>>(lhs, Xbf, MAIN_ROWS * H_ / 4);
  adapter1_k<<<B_ * NSEG_, 256, 0, stream>>>(lhs, starts, Bm, interb);
  adapter2_k<<<B_ * NSEG_ * 8, 256, 0, stream>>>(interb, Am, bias, Xbf);
  ce_gemm_k<<<dim3(V_ / BN, MROWS / BM), 256, 0, stream>>>(Xbf, Wbf, rowsum);
  tlogit_k<<<MROWS, 256, 0, stream>>>(Xbf, Wbf, input_ids, mlabels, tlog);
  finalize_k<<<1, 256, 0, stream>>>(rowsum, tlog, attn, starts, ends, mmask, out);
}

// Round 3
// 1589.397 us; speedup vs baseline: 2.2505x; 1.1708x over previous
//
#include <hip/hip_runtime.h>

typedef __bf16 bf16x8 __attribute__((ext_vector_type(8)));
typedef float f32x4 __attribute__((ext_vector_type(4)));
typedef int i32x4 __attribute__((ext_vector_type(4)));

#define B_ 2
#define S_ 2048
#define H_ 2048
#define V_ 32000
#define NSEG_ 16
#define R_ 256
#define TM_ 1024
#define MAIN_ROWS 4096          // B*S
#define MROWS 6144              // B*S + B*TM

__device__ __forceinline__ unsigned short f2bf(float f) {
  union { float f; unsigned u; } v; v.f = f;
  unsigned r = (v.u + 0x7fffu + ((v.u >> 16) & 1u)) >> 16;
  return (unsigned short)r;
}

__device__ __forceinline__ i32x4 pack8(const float* __restrict__ src) {
  float4 v0 = *(const float4*)src;
  float4 v1 = *(const float4*)(src + 4);
  union { unsigned short u[8]; i32x4 v; } o;
  o.u[0] = f2bf(v0.x); o.u[1] = f2bf(v0.y); o.u[2] = f2bf(v0.z); o.u[3] = f2bf(v0.w);
  o.u[4] = f2bf(v1.x); o.u[5] = f2bf(v1.y); o.u[6] = f2bf(v1.z); o.u[7] = f2bf(v1.w);
  return o.v;
}

// ---------------- f32 -> bf16 convert (vectorized) ----------------
__global__ void f32_to_bf16_k(const float* __restrict__ in,
                              unsigned short* __restrict__ out, int n4) {
  int i = blockIdx.x * 256 + threadIdx.x;
  if (i < n4) {
    float4 v = ((const float4*)in)[i];
    ushort4 o;
    o.x = f2bf(v.x); o.y = f2bf(v.y); o.z = f2bf(v.z); o.w = f2bf(v.w);
    ((ushort4*)out)[i] = o;
  }
}

// ---------------- adapter stage 1: inter = x @ Bm^T  (grouped MFMA GEMM) ----------------
__global__ __launch_bounds__(256)
void adapter1_k(const float* __restrict__ lhs, const int* __restrict__ starts,
                const float* __restrict__ Bm, unsigned short* __restrict__ interb) {
  const int g = blockIdx.x;
  const int b = g >> 4, seg = g & 15;
  __shared__ __align__(16) unsigned short At[64 * 72];
  __shared__ __align__(16) unsigned short Bt[256 * 72];
  const int tid = threadIdx.x;
  const int wave = tid >> 6, lane = tid & 63;
  const int quad = lane >> 4, l16 = lane & 15;
  const int start = starts[b];

  f32x4 acc[4][4];
  for (int i = 0; i < 4; ++i)
    for (int j = 0; j < 4; ++j)
      acc[i][j] = (f32x4){0.f, 0.f, 0.f, 0.f};

  for (int k0 = 0; k0 < H_; k0 += 64) {
    for (int i = 0; i < 2; ++i) {
      int c = tid + i * 256;
      int row = c >> 3, p = c & 7;
      int t = seg * 64 + row;
      const float* src = lhs + ((size_t)b * S_ + start + t) * H_ + k0 + p * 8;
      *(i32x4*)(&At[row * 72 + p * 8]) = pack8(src);
    }
    for (int i = 0; i < 8; ++i) {
      int c = tid + i * 256;
      int row = c >> 3, p = c & 7;
      const float* src = Bm + ((size_t)seg * R_ + row) * H_ + k0 + p * 8;
      *(i32x4*)(&Bt[row * 72 + p * 8]) = pack8(src);
    }
    __syncthreads();
    for (int kk = 0; kk < 64; kk += 32) {
      bf16x8 af[4], bfr[4];
      for (int rt = 0; rt < 4; ++rt)
        af[rt] = __builtin_bit_cast(bf16x8,
            *(const i32x4*)(&At[(rt * 16 + l16) * 72 + kk + quad * 8]));
      for (int ct = 0; ct < 4; ++ct)
        bfr[ct] = __builtin_bit_cast(bf16x8,
            *(const i32x4*)(&Bt[(wave * 64 + ct * 16 + l16) * 72 + kk + quad * 8]));
      for (int rt = 0; rt < 4; ++rt)
        for (int ct = 0; ct < 4; ++ct)
          acc[rt][ct] = __builtin_amdgcn_mfma_f32_16x16x32_bf16(
              af[rt], bfr[ct], acc[rt][ct], 0, 0, 0);
    }
    __syncthreads();
  }
  for (int rt = 0; rt < 4; ++rt)
    for (int ct = 0; ct < 4; ++ct)
      for (int r = 0; r < 4; ++r) {
        int m = rt * 16 + quad * 4 + r;
        int n = wave * 64 + ct * 16 + l16;
        interb[((size_t)g * 64 + m) * R_ + n] = f2bf(acc[rt][ct][r]);
      }
}

// ---------------- adapter stage 2: trans = inter @ Am^T + bias -> Xbf ----------------
__global__ __launch_bounds__(256)
void adapter2_k(const unsigned short* __restrict__ interb, const float* __restrict__ Am,
                const float* __restrict__ bias, unsigned short* __restrict__ Xbf) {
  const int g = blockIdx.x >> 3;
  const int nt = blockIdx.x & 7;
  const int seg = g & 15;
  __shared__ __align__(16) unsigned short At[64 * 72];
  __shared__ __align__(16) unsigned short Bt[256 * 72];
  const int tid = threadIdx.x;
  const int wave = tid >> 6, lane = tid & 63;
  const int quad = lane >> 4, l16 = lane & 15;

  f32x4 acc[4][4];
  for (int i = 0; i < 4; ++i)
    for (int j = 0; j < 4; ++j)
      acc[i][j] = (f32x4){0.f, 0.f, 0.f, 0.f};

  for (int k0 = 0; k0 < R_; k0 += 64) {
    for (int i = 0; i < 2; ++i) {
      int c = tid + i * 256;
      int row = c >> 3, p = c & 7;
      *(i32x4*)(&At[row * 72 + p * 8]) =
          *(const i32x4*)(interb + ((size_t)g * 64 + row) * R_ + k0 + p * 8);
    }
    for (int i = 0; i < 8; ++i) {
      int c = tid + i * 256;
      int row = c >> 3, p = c & 7;
      const float* src = Am + ((size_t)seg * H_ + nt * 256 + row) * R_ + k0 + p * 8;
      *(i32x4*)(&Bt[row * 72 + p * 8]) = pack8(src);
    }
    __syncthreads();
    for (int kk = 0; kk < 64; kk += 32) {
      bf16x8 af[4], bfr[4];
      for (int rt = 0; rt < 4; ++rt)
        af[rt] = __builtin_bit_cast(bf16x8,
            *(const i32x4*)(&At[(rt * 16 + l16) * 72 + kk + quad * 8]));
      for (int ct = 0; ct < 4; ++ct)
        bfr[ct] = __builtin_bit_cast(bf16x8,
            *(const i32x4*)(&Bt[(wave * 64 + ct * 16 + l16) * 72 + kk + quad * 8]));
      for (int rt = 0; rt < 4; ++rt)
        for (int ct = 0; ct < 4; ++ct)
          acc[rt][ct] = __builtin_amdgcn_mfma_f32_16x16x32_bf16(
              af[rt], bfr[ct], acc[rt][ct], 0, 0, 0);
    }
    __syncthreads();
  }
  for (int rt = 0; rt < 4; ++rt)
    for (int ct = 0; ct < 4; ++ct)
      for (int r = 0; r < 4; ++r) {
        int m = rt * 16 + quad * 4 + r;
        int h = nt * 256 + wave * 64 + ct * 16 + l16;
        float v = acc[rt][ct][r] + bias[seg * H_ + h];
        Xbf[((size_t)(MAIN_ROWS + g * 64 + m)) * H_ + h] = f2bf(v);
      }
}

// ---------------- fused CE GEMM: rowsum[m] += sum_n exp(X[m]·W[n]) ----------------
// grid: x = m-panels (48, fastest-varying -> W-panel reuse + per-XCD X residency),
//       y = n-panels (250). global_load_lds width=16, XOR-swizzled LDS chunks.
#define BM 128
#define BN 128
#define BK 64

__global__ __launch_bounds__(256)
void ce_gemm_k(const unsigned short* __restrict__ X, const unsigned short* __restrict__ Wb,
               const int* __restrict__ starts, float* __restrict__ rowsum) {
  const int m0 = blockIdx.x * BM;
  const int n0 = blockIdx.y * BN;
  // early-exit: main-sequence rows entirely before starts[b]-1 feed no loss term
  if (m0 < MAIN_ROWS) {
    int b = m0 >> 11;
    if (m0 + BM - 1 < starts[b] - 1) return;
  }
  __shared__ __align__(16) unsigned short At[BM * BK];
  __shared__ __align__(16) unsigned short Bt[BN * BK];
  const int tid = threadIdx.x;
  const int wave = tid >> 6, lane = tid & 63;
  const int quad = lane >> 4, l16 = lane & 15;
  const int wrow = (wave >> 1) * 64, wcol = (wave & 1) * 64;

  const int rsub = lane >> 3;                    // row within 8-row group
  const int clog = (lane & 7) ^ rsub;            // XOR chunk swizzle
  const unsigned short* ag = X + (size_t)(m0 + 32 * wave + rsub) * H_ + clog * 8;
  const unsigned short* bg = Wb + (size_t)(n0 + 32 * wave + rsub) * H_ + clog * 8;
  unsigned short* al = &At[(32 * wave) * BK];
  unsigned short* bl = &Bt[(32 * wave) * BK];

  f32x4 acc[4][4];
  for (int i = 0; i < 4; ++i)
    for (int j = 0; j < 4; ++j)
      acc[i][j] = (f32x4){0.f, 0.f, 0.f, 0.f};

  for (int k0 = 0; k0 < H_; k0 += BK) {
    #pragma unroll
    for (int j = 0; j < 4; ++j) {
      __builtin_amdgcn_global_load_lds(
          (const __attribute__((address_space(1))) void*)(ag + (size_t)(8 * j) * H_ + k0),
          (__attribute__((address_space(3))) void*)(al + 8 * j * BK), 16, 0, 0);
      __builtin_amdgcn_global_load_lds(
          (const __attribute__((address_space(1))) void*)(bg + (size_t)(8 * j) * H_ + k0),
          (__attribute__((address_space(3))) void*)(bl + 8 * j * BK), 16, 0, 0);
    }
    __syncthreads();
    #pragma unroll
    for (int kk = 0; kk < BK; kk += 32) {
      const int p = ((kk >> 3) + quad) ^ (l16 & 7);   // de-swizzle
      bf16x8 af[4], bfr[4];
      #pragma unroll
      for (int rt = 0; rt < 4; ++rt)
        af[rt] = __builtin_bit_cast(bf16x8,
            *(const i32x4*)(&At[(wrow + rt * 16 + l16) * BK + p * 8]));
      #pragma unroll
      for (int ct = 0; ct < 4; ++ct)
        bfr[ct] = __builtin_bit_cast(bf16x8,
            *(const i32x4*)(&Bt[(wcol + ct * 16 + l16) * BK + p * 8]));
      #pragma unroll
      for (int rt = 0; rt < 4; ++rt)
        #pragma unroll
        for (int ct = 0; ct < 4; ++ct)
          acc[rt][ct] = __builtin_amdgcn_mfma_f32_16x16x32_bf16(
              af[rt], bfr[ct], acc[rt][ct], 0, 0, 0);
    }
    __syncthreads();
  }

  for (int rt = 0; rt < 4; ++rt) {
    float s[4] = {0.f, 0.f, 0.f, 0.f};
    for (int ct = 0; ct < 4; ++ct)
      for (int r = 0; r < 4; ++r)
        s[r] += __expf(acc[rt][ct][r]);
    for (int m = 1; m < 16; m <<= 1)
      for (int r = 0; r < 4; ++r)
        s[r] += __shfl_xor(s[r], m, 64);
    if (l16 == 0) {
      for (int r = 0; r < 4; ++r) {
        int grow = m0 + wrow + rt * 16 + quad * 4 + r;
        atomicAdd(&rowsum[grow], s[r]);
      }
    }
  }
}

// ---------------- target logit per token row ----------------
__global__ void tlogit_k(const unsigned short* __restrict__ Xbf,
                         const unsigned short* __restrict__ Wbf,
                         const int* __restrict__ input_ids,
                         const int* __restrict__ mlabels,
                         float* __restrict__ tlog) {
  int i = blockIdx.x;
  int label;
  if (i < MAIN_ROWS) {
    int b = i >> 11, s = i & 2047;
    label = (s < S_ - 1) ? input_ids[b * S_ + s + 1] : 0;
  } else {
    int j = i - MAIN_ROWS;
    int b = j >> 10, t = j & 1023;
    label = mlabels[b * TM_ + t];
  }
  const unsigned short* x = Xbf + (size_t)i * H_;
  const unsigned short* w = Wbf + (size_t)label * H_;
  int tid = threadIdx.x;
  i32x4 xv = *(const i32x4*)(x + tid * 8);
  i32x4 wv = *(const i32x4*)(w + tid * 8);
  float acc = 0.f;
  for (int q = 0; q < 4; ++q) {
    unsigned xu = (unsigned)xv[q], wu = (unsigned)wv[q];
    float x0 = __uint_as_float(xu << 16), x1 = __uint_as_float(xu & 0xffff0000u);
    float w0 = __uint_as_float(wu << 16), w1 = __uint_as_float(wu & 0xffff0000u);
    acc += x0 * w0 + x1 * w1;
  }
  for (int m = 1; m < 64; m <<= 1) acc += __shfl_xor(acc, m, 64);
  __shared__ float red[4];
  if ((tid & 63) == 0) red[tid >> 6] = acc;
  __syncthreads();
  if (tid == 0) tlog[i] = red[0] + red[1] + red[2] + red[3];
}

// ---------------- final masked means ----------------
__global__ void finalize_k(const float* __restrict__ rowsum, const float* __restrict__ tlog,
                           const int* __restrict__ attn, const int* __restrict__ starts,
                           const int* __restrict__ ends, const int* __restrict__ mmask,
                           float* __restrict__ out) {
  int tid = threadIdx.x;
  __shared__ int tmp[8];
  __shared__ float red[24];
  int s0 = 0, s1 = 0;
  for (int s = tid; s < S_; s += 256) { s0 += attn[s]; s1 += attn[S_ + s]; }
  for (int m = 1; m < 64; m <<= 1) { s0 += __shfl_xor(s0, m, 64); s1 += __shfl_xor(s1, m, 64); }
  if ((tid & 63) == 0) { tmp[(tid >> 6) * 2] = s0; tmp[(tid >> 6) * 2 + 1] = s1; }
  __syncthreads();
  int rl[2];
  rl[0] = tmp[0] + tmp[2] + tmp[4] + tmp[6];
  rl[1] = tmp[1] + tmp[3] + tmp[5] + tmp[7];

  float st_s = 0.f, st_c = 0.f, fa_s = 0.f, fa_c = 0.f, m_s = 0.f, m_c = 0.f;
  for (int i = tid; i < MAIN_ROWS; i += 256) {
    int b = i >> 11, s = i & 2047;
    if (s < S_ - 1) {
      bool stm = (s >= starts[b] - 1) && (s <= ends[b] - 1);
      bool fam = (s >= ends[b]) && (s < rl[b] - 1);
      if (stm || fam) {
        float nll = logf(rowsum[i]) - tlog[i];
        if (stm) { st_s += nll; st_c += 1.f; }
        if (fam) { fa_s += nll; fa_c += 1.f; }
      }
    }
  }
  for (int i = tid; i < B_ * TM_; i += 256) {
    int row = MAIN_ROWS + i;
    float nll = logf(rowsum[row]) - tlog[row];
    float m = (float)mmask[i];
    m_s += nll * m; m_c += m;
  }
  float vals[6] = {st_s, st_c, fa_s, fa_c, m_s, m_c};
  for (int m = 1; m < 64; m <<= 1)
    for (int q = 0; q < 6; ++q) vals[q] += __shfl_xor(vals[q], m, 64);
  if ((tid & 63) == 0)
    for (int q = 0; q < 6; ++q) red[(tid >> 6) * 6 + q] = vals[q];
  __syncthreads();
  if (tid == 0) {
    float stS = red[0] + red[6] + red[12] + red[18];
    float stC = red[1] + red[7] + red[13] + red[19];
    float faS = red[2] + red[8] + red[14] + red[20];
    float faC = red[3] + red[9] + red[15] + red[21];
    float mS  = red[4] + red[10] + red[16] + red[22];
    float mC  = red[5] + red[11] + red[17] + red[23];
    float st = stS / fmaxf(stC, 1.f);
    float fa = faS / fmaxf(faC, 1.f);
    float ml = mS / fmaxf(mC, 1.f);
    out[0] = 0.5f * ml + 0.5f * st + 0.4f * fa;
    out[1] = ml;
    out[2] = st;
    out[3] = fa;
  }
}

extern "C" void kernel_launch(void* const* d_in, const int* in_sizes, int n_in,
                              void* d_out, int out_size, void* d_ws, size_t ws_size,
                              hipStream_t stream) {
  (void)in_sizes; (void)n_in; (void)out_size; (void)ws_size;
  const float* lhs      = (const float*)d_in[0];
  const int* input_ids  = (const int*)d_in[1];
  const int* attn       = (const int*)d_in[2];
  const int* starts     = (const int*)d_in[3];
  const int* ends       = (const int*)d_in[4];
  const int* mlabels    = (const int*)d_in[5];
  const int* mmask      = (const int*)d_in[6];
  const float* Am       = (const float*)d_in[8];
  const float* Bm       = (const float*)d_in[9];
  const float* bias     = (const float*)d_in[10];
  const float* Wf       = (const float*)d_in[11];
  float* out = (float*)d_out;

  char* ws = (char*)d_ws;
  unsigned short* Wbf   = (unsigned short*)ws;                  // 131,072,000 B
  unsigned short* Xbf   = (unsigned short*)(ws + 131072000);    //  25,165,824 B
  unsigned short* interb= (unsigned short*)(ws + 156237824);    //   1,048,576 B
  float* rowsum         = (float*)(ws + 157286400);             //      24,576 B
  float* tlog           = (float*)(ws + 157310976);             //      24,576 B

  hipMemsetAsync(rowsum, 0, MROWS * sizeof(float), stream);
  f32_to_bf16_k<<<(V_ * H_ / 4 + 255) / 256, 256, 0, stream>>>(Wf, Wbf, V_ * H_ / 4);
  f32_to_bf16_k<<<(MAIN_ROWS * H_ / 4 + 255) / 256, 256, 0, stream>>>(lhs, Xbf, MAIN_ROWS * H_ / 4);
  adapter1_k<<<B_ * NSEG_, 256, 0, stream>>>(lhs, starts, Bm, interb);
  adapter2_k<<<B_ * NSEG_ * 8, 256, 0, stream>>>(interb, Am, bias, Xbf);
  ce_gemm_k<<<dim3(MROWS / BM, V_ / BN), 256, 0, stream>>>(Xbf, Wbf, starts, rowsum);
  tlogit_k<<<MROWS, 256, 0, stream>>>(Xbf, Wbf, input_ids, mlabels, tlog);
  finalize_k<<<1, 256, 0, stream>>>(rowsum, tlog, attn, starts, ends, mmask, out);
}

// Round 4
// 1026.558 us; speedup vs baseline: 3.4844x; 1.5483x over previous
//
#include <hip/hip_runtime.h>

typedef __bf16 bf16x8 __attribute__((ext_vector_type(8)));
typedef float f32x4 __attribute__((ext_vector_type(4)));
typedef float f32x2 __attribute__((ext_vector_type(2)));
typedef int i32x4 __attribute__((ext_vector_type(4)));
typedef int i32x2 __attribute__((ext_vector_type(2)));
typedef int i32x8 __attribute__((ext_vector_type(8)));

#define B_ 2
#define S_ 2048
#define H_ 2048
#define V_ 32000
#define NSEG_ 16
#define R_ 256
#define TM_ 1024
#define MAIN_ROWS 4096          // B*S
#define MROWS 6144              // B*S + B*TM

// W is quantized as Wq = fp8(W * 2^9); the 2^-9 is folded into the MFMA
// B-operand E8M0 block scale (byte 118 = 2^-9). A-operand scale = 127 (2^0).
#define WSCALE 512.0f
#define WSCALE_INV 0.001953125f

__device__ __forceinline__ unsigned short f2bf(float f) {
  union { float f; unsigned u; } v; v.f = f;
  unsigned r = (v.u + 0x7fffu + ((v.u >> 16) & 1u)) >> 16;
  return (unsigned short)r;
}

__device__ __forceinline__ i32x4 pack8(const float* __restrict__ src) {
  float4 v0 = *(const float4*)src;
  float4 v1 = *(const float4*)(src + 4);
  union { unsigned short u[8]; i32x4 v; } o;
  o.u[0] = f2bf(v0.x); o.u[1] = f2bf(v0.y); o.u[2] = f2bf(v0.z); o.u[3] = f2bf(v0.w);
  o.u[4] = f2bf(v1.x); o.u[5] = f2bf(v1.y); o.u[6] = f2bf(v1.z); o.u[7] = f2bf(v1.w);
  return o.v;
}

// ---- fp8 e4m3 helpers (HW cvt if available, manual fallback) ----
__device__ __forceinline__ unsigned e4m3_enc(float f) {
  unsigned u = __float_as_uint(f);
  unsigned s = (u >> 24) & 0x80u;
  float a = fabsf(f);
  unsigned mag;
  if (a >= 0.015625f) {
    unsigned b = __float_as_uint(a);
    b += 0x7FFFFu + ((b >> 20) & 1u);       // RNE at 3-bit mantissa
    int e = (int)(b >> 23) - 120;
    unsigned m = (b >> 20) & 7u;
    if (e > 15) { e = 15; m = 6; }          // clamp to 448
    mag = ((unsigned)e << 3) | m;
  } else {
    mag = (unsigned)__float2int_rn(a * 512.f);  // subnormal grid 2^-9
  }
  return s | mag;
}

__device__ __forceinline__ float e4m3_dec(unsigned b) {
  unsigned e = (b >> 3) & 15u, m = b & 7u;
  float mag = e ? __uint_as_float(((e + 120u) << 23) | (m << 20))
                : (float)m * 0.001953125f;
  return (b & 0x80u) ? -mag : mag;
}

__device__ __forceinline__ int pk_fp8x4(float a, float b, float c, float d) {
#if __has_builtin(__builtin_amdgcn_cvt_pk_fp8_f32)
  int w = __builtin_amdgcn_cvt_pk_fp8_f32(a, b, 0, false);
  w = __builtin_amdgcn_cvt_pk_fp8_f32(c, d, w, true);
  return w;
#else
  return (int)e4m3_enc(a) | ((int)e4m3_enc(b) << 8) |
         ((int)e4m3_enc(c) << 16) | ((int)e4m3_enc(d) << 24);
#endif
}

__device__ __forceinline__ unsigned char fp8_1(float v) {
#if __has_builtin(__builtin_amdgcn_cvt_pk_fp8_f32)
  int w = __builtin_amdgcn_cvt_pk_fp8_f32(v, 0.f, 0, false);
  return (unsigned char)(w & 0xff);
#else
  return (unsigned char)e4m3_enc(v);
#endif
}

__device__ __forceinline__ void fp8x4_dec(int v, float* o) {
#if __has_builtin(__builtin_amdgcn_cvt_pk_f32_fp8)
  f32x2 lo = __builtin_amdgcn_cvt_pk_f32_fp8(v, false);
  f32x2 hi = __builtin_amdgcn_cvt_pk_f32_fp8(v, true);
  o[0] = lo[0]; o[1] = lo[1]; o[2] = hi[0]; o[3] = hi[1];
#else
  o[0] = e4m3_dec(v & 0xff); o[1] = e4m3_dec((v >> 8) & 0xff);
  o[2] = e4m3_dec((v >> 16) & 0xff); o[3] = e4m3_dec((v >> 24) & 0xff);
#endif
}

// ---------------- f32 -> fp8 quantize (16 elems/thread) ----------------
__global__ void quant_fp8_k(const float* __restrict__ in, int* __restrict__ out,
                            float scale, int n16) {
  int i = blockIdx.x * 256 + threadIdx.x;
  if (i >= n16) return;
  const float4* p = (const float4*)in + (size_t)i * 4;
  float4 v0 = p[0], v1 = p[1], v2 = p[2], v3 = p[3];
  i32x4 o;
  o[0] = pk_fp8x4(v0.x * scale, v0.y * scale, v0.z * scale, v0.w * scale);
  o[1] = pk_fp8x4(v1.x * scale, v1.y * scale, v1.z * scale, v1.w * scale);
  o[2] = pk_fp8x4(v2.x * scale, v2.y * scale, v2.z * scale, v2.w * scale);
  o[3] = pk_fp8x4(v3.x * scale, v3.y * scale, v3.z * scale, v3.w * scale);
  *((i32x4*)out + i) = o;
}

// ---------------- adapter stage 1: inter = x @ Bm^T  (bf16 MFMA) ----------------
__global__ __launch_bounds__(256)
void adapter1_k(const float* __restrict__ lhs, const int* __restrict__ starts,
                const float* __restrict__ Bm, unsigned short* __restrict__ interb) {
  const int g = blockIdx.x;
  const int b = g >> 4, seg = g & 15;
  __shared__ __align__(16) unsigned short At[64 * 72];
  __shared__ __align__(16) unsigned short Bt[256 * 72];
  const int tid = threadIdx.x;
  const int wave = tid >> 6, lane = tid & 63;
  const int quad = lane >> 4, l16 = lane & 15;
  const int start = starts[b];

  f32x4 acc[4][4];
  for (int i = 0; i < 4; ++i)
    for (int j = 0; j < 4; ++j)
      acc[i][j] = (f32x4){0.f, 0.f, 0.f, 0.f};

  for (int k0 = 0; k0 < H_; k0 += 64) {
    for (int i = 0; i < 2; ++i) {
      int c = tid + i * 256;
      int row = c >> 3, p = c & 7;
      int t = seg * 64 + row;
      const float* src = lhs + ((size_t)b * S_ + start + t) * H_ + k0 + p * 8;
      *(i32x4*)(&At[row * 72 + p * 8]) = pack8(src);
    }
    for (int i = 0; i < 8; ++i) {
      int c = tid + i * 256;
      int row = c >> 3, p = c & 7;
      const float* src = Bm + ((size_t)seg * R_ + row) * H_ + k0 + p * 8;
      *(i32x4*)(&Bt[row * 72 + p * 8]) = pack8(src);
    }
    __syncthreads();
    for (int kk = 0; kk < 64; kk += 32) {
      bf16x8 af[4], bfr[4];
      for (int rt = 0; rt < 4; ++rt)
        af[rt] = __builtin_bit_cast(bf16x8,
            *(const i32x4*)(&At[(rt * 16 + l16) * 72 + kk + quad * 8]));
      for (int ct = 0; ct < 4; ++ct)
        bfr[ct] = __builtin_bit_cast(bf16x8,
            *(const i32x4*)(&Bt[(wave * 64 + ct * 16 + l16) * 72 + kk + quad * 8]));
      for (int rt = 0; rt < 4; ++rt)
        for (int ct = 0; ct < 4; ++ct)
          acc[rt][ct] = __builtin_amdgcn_mfma_f32_16x16x32_bf16(
              af[rt], bfr[ct], acc[rt][ct], 0, 0, 0);
    }
    __syncthreads();
  }
  for (int rt = 0; rt < 4; ++rt)
    for (int ct = 0; ct < 4; ++ct)
      for (int r = 0; r < 4; ++r) {
        int m = rt * 16 + quad * 4 + r;
        int n = wave * 64 + ct * 16 + l16;
        interb[((size_t)g * 64 + m) * R_ + n] = f2bf(acc[rt][ct][r]);
      }
}

// ---------------- adapter stage 2: trans = inter @ Am^T + bias -> Xq (fp8) ----------------
__global__ __launch_bounds__(256)
void adapter2_k(const unsigned short* __restrict__ interb, const float* __restrict__ Am,
                const float* __restrict__ bias, unsigned char* __restrict__ Xq) {
  const int g = blockIdx.x >> 3;
  const int nt = blockIdx.x & 7;
  const int seg = g & 15;
  __shared__ __align__(16) unsigned short At[64 * 72];
  __shared__ __align__(16) unsigned short Bt[256 * 72];
  const int tid = threadIdx.x;
  const int wave = tid >> 6, lane = tid & 63;
  const int quad = lane >> 4, l16 = lane & 15;

  f32x4 acc[4][4];
  for (int i = 0; i < 4; ++i)
    for (int j = 0; j < 4; ++j)
      acc[i][j] = (f32x4){0.f, 0.f, 0.f, 0.f};

  for (int k0 = 0; k0 < R_; k0 += 64) {
    for (int i = 0; i < 2; ++i) {
      int c = tid + i * 256;
      int row = c >> 3, p = c & 7;
      *(i32x4*)(&At[row * 72 + p * 8]) =
          *(const i32x4*)(interb + ((size_t)g * 64 + row) * R_ + k0 + p * 8);
    }
    for (int i = 0; i < 8; ++i) {
      int c = tid + i * 256;
      int row = c >> 3, p = c & 7;
      const float* src = Am + ((size_t)seg * H_ + nt * 256 + row) * R_ + k0 + p * 8;
      *(i32x4*)(&Bt[row * 72 + p * 8]) = pack8(src);
    }
    __syncthreads();
    for (int kk = 0; kk < 64; kk += 32) {
      bf16x8 af[4], bfr[4];
      for (int rt = 0; rt < 4; ++rt)
        af[rt] = __builtin_bit_cast(bf16x8,
            *(const i32x4*)(&At[(rt * 16 + l16) * 72 + kk + quad * 8]));
      for (int ct = 0; ct < 4; ++ct)
        bfr[ct] = __builtin_bit_cast(bf16x8,
            *(const i32x4*)(&Bt[(wave * 64 + ct * 16 + l16) * 72 + kk + quad * 8]));
      for (int rt = 0; rt < 4; ++rt)
        for (int ct = 0; ct < 4; ++ct)
          acc[rt][ct] = __builtin_amdgcn_mfma_f32_16x16x32_bf16(
              af[rt], bfr[ct], acc[rt][ct], 0, 0, 0);
    }
    __syncthreads();
  }
  for (int rt = 0; rt < 4; ++rt)
    for (int ct = 0; ct < 4; ++ct)
      for (int r = 0; r < 4; ++r) {
        int m = rt * 16 + quad * 4 + r;
        int h = nt * 256 + wave * 64 + ct * 16 + l16;
        float v = acc[rt][ct][r] + bias[seg * H_ + h];
        Xq[((size_t)(MAIN_ROWS + g * 64 + m)) * H_ + h] = fp8_1(v);
      }
}

// ---------------- fused CE GEMM (MX-fp8, K=128): rowsum[m] += sum_n exp(X[m]·W[n]) ----------------
#define BM 128
#define BN 128
#define BKB 128    // K-tile: 128 fp8 elems = 128 B per row (same byte layout as bf16 BK=64)

__global__ __launch_bounds__(256)
void ce_gemm_k(const unsigned char* __restrict__ X, const unsigned char* __restrict__ Wq,
               const int* __restrict__ starts, float* __restrict__ rowsum) {
  const int m0 = blockIdx.x * BM;
  const int n0 = blockIdx.y * BN;
  if (m0 < MAIN_ROWS) {
    int b = m0 >> 11;
    if (m0 + BM - 1 < starts[b] - 1) return;   // fully-masked main-row panel
  }
  __shared__ __align__(16) unsigned char At[BM * BKB];
  __shared__ __align__(16) unsigned char Bt[BN * BKB];
  const int tid = threadIdx.x;
  const int wave = tid >> 6, lane = tid & 63;
  const int quad = lane >> 4, l16 = lane & 15;
  const int wrow = (wave >> 1) * 64, wcol = (wave & 1) * 64;

  const int rsub = lane >> 3;                 // row within 8-row DMA group
  const int clog = (lane & 7) ^ rsub;         // XOR 16B-chunk swizzle
  const unsigned char* ag = X  + (size_t)(m0 + 32 * wave + rsub) * H_ + clog * 16;
  const unsigned char* bg = Wq + (size_t)(n0 + 32 * wave + rsub) * H_ + clog * 16;
  unsigned char* al = &At[(32 * wave) * BKB];
  unsigned char* bl = &Bt[(32 * wave) * BKB];

  f32x4 acc[4][4];
  for (int i = 0; i < 4; ++i)
    for (int j = 0; j < 4; ++j)
      acc[i][j] = (f32x4){0.f, 0.f, 0.f, 0.f};

  const int r7 = l16 & 7;
  const int p0 = (2 * quad) ^ r7;             // physical chunk of logical 2q
  const int p1 = (2 * quad + 1) ^ r7;         // physical chunk of logical 2q+1

  for (int k0 = 0; k0 < H_; k0 += BKB) {
    #pragma unroll
    for (int j = 0; j < 4; ++j) {
      __builtin_amdgcn_global_load_lds(
          (const __attribute__((address_space(1))) void*)(ag + (size_t)(8 * j) * H_ + k0),
          (__attribute__((address_space(3))) void*)(al + 8 * j * BKB), 16, 0, 0);
      __builtin_amdgcn_global_load_lds(
          (const __attribute__((address_space(1))) void*)(bg + (size_t)(8 * j) * H_ + k0),
          (__attribute__((address_space(3))) void*)(bl + 8 * j * BKB), 16, 0, 0);
    }
    __syncthreads();
    i32x8 af[4], bfr[4];
    #pragma unroll
    for (int rt = 0; rt < 4; ++rt) {
      const unsigned char* base = &At[(wrow + rt * 16 + l16) * BKB];
      i32x4 lo = *(const i32x4*)(base + p0 * 16);
      i32x4 hi = *(const i32x4*)(base + p1 * 16);
      i32x8 t;
      t[0] = lo[0]; t[1] = lo[1]; t[2] = lo[2]; t[3] = lo[3];
      t[4] = hi[0]; t[5] = hi[1]; t[6] = hi[2]; t[7] = hi[3];
      af[rt] = t;
    }
    #pragma unroll
    for (int ct = 0; ct < 4; ++ct) {
      const unsigned char* base = &Bt[(wcol + ct * 16 + l16) * BKB];
      i32x4 lo = *(const i32x4*)(base + p0 * 16);
      i32x4 hi = *(const i32x4*)(base + p1 * 16);
      i32x8 t;
      t[0] = lo[0]; t[1] = lo[1]; t[2] = lo[2]; t[3] = lo[3];
      t[4] = hi[0]; t[5] = hi[1]; t[6] = hi[2]; t[7] = hi[3];
      bfr[ct] = t;
    }
    #pragma unroll
    for (int rt = 0; rt < 4; ++rt)
      #pragma unroll
      for (int ct = 0; ct < 4; ++ct)
        acc[rt][ct] = __builtin_amdgcn_mfma_scale_f32_16x16x128_f8f6f4(
            af[rt], bfr[ct], acc[rt][ct],
            0 /*A=fp8*/, 0 /*B=fp8*/, 0, 127 /*A scale 2^0*/, 0, 118 /*B scale 2^-9*/);
    __syncthreads();
  }

  for (int rt = 0; rt < 4; ++rt) {
    float s[4] = {0.f, 0.f, 0.f, 0.f};
    for (int ct = 0; ct < 4; ++ct)
      for (int r = 0; r < 4; ++r)
        s[r] += __expf(acc[rt][ct][r]);
    for (int m = 1; m < 16; m <<= 1)
      for (int r = 0; r < 4; ++r)
        s[r] += __shfl_xor(s[r], m, 64);
    if (l16 == 0) {
      for (int r = 0; r < 4; ++r) {
        int grow = m0 + wrow + rt * 16 + quad * 4 + r;
        atomicAdd(&rowsum[grow], s[r]);
      }
    }
  }
}

// ---------------- target logit per token row (fp8 dequant dot) ----------------
__global__ void tlogit_k(const unsigned char* __restrict__ Xq,
                         const unsigned char* __restrict__ Wq,
                         const int* __restrict__ input_ids,
                         const int* __restrict__ mlabels,
                         float* __restrict__ tlog) {
  int i = blockIdx.x;
  int label;
  if (i < MAIN_ROWS) {
    int b = i >> 11, s = i & 2047;
    label = (s < S_ - 1) ? input_ids[b * S_ + s + 1] : 0;
  } else {
    int j = i - MAIN_ROWS;
    int b = j >> 10, t = j & 1023;
    label = mlabels[b * TM_ + t];
  }
  const unsigned char* x = Xq + (size_t)i * H_;
  const unsigned char* w = Wq + (size_t)label * H_;
  int tid = threadIdx.x;
  i32x2 xv = *(const i32x2*)(x + tid * 8);
  i32x2 wv = *(const i32x2*)(w + tid * 8);
  float acc = 0.f;
  for (int q = 0; q < 2; ++q) {
    float xf[4], wf[4];
    fp8x4_dec(xv[q], xf);
    fp8x4_dec(wv[q], wf);
    acc += xf[0] * wf[0] + xf[1] * wf[1] + xf[2] * wf[2] + xf[3] * wf[3];
  }
  for (int m = 1; m < 64; m <<= 1) acc += __shfl_xor(acc, m, 64);
  __shared__ float red[4];
  if ((tid & 63) == 0) red[tid >> 6] = acc;
  __syncthreads();
  if (tid == 0) tlog[i] = (red[0] + red[1] + red[2] + red[3]) * WSCALE_INV;
}

// ---------------- final masked means ----------------
__global__ void finalize_k(const float* __restrict__ rowsum, const float* __restrict__ tlog,
                           const int* __restrict__ attn, const int* __restrict__ starts,
                           const int* __restrict__ ends, const int* __restrict__ mmask,
                           float* __restrict__ out) {
  int tid = threadIdx.x;
  __shared__ int tmp[8];
  __shared__ float red[24];
  int s0 = 0, s1 = 0;
  for (int s = tid; s < S_; s += 256) { s0 += attn[s]; s1 += attn[S_ + s]; }
  for (int m = 1; m < 64; m <<= 1) { s0 += __shfl_xor(s0, m, 64); s1 += __shfl_xor(s1, m, 64); }
  if ((tid & 63) == 0) { tmp[(tid >> 6) * 2] = s0; tmp[(tid >> 6) * 2 + 1] = s1; }
  __syncthreads();
  int rl[2];
  rl[0] = tmp[0] + tmp[2] + tmp[4] + tmp[6];
  rl[1] = tmp[1] + tmp[3] + tmp[5] + tmp[7];

  float st_s = 0.f, st_c = 0.f, fa_s = 0.f, fa_c = 0.f, m_s = 0.f, m_c = 0.f;
  for (int i = tid; i < MAIN_ROWS; i += 256) {
    int b = i >> 11, s = i & 2047;
    if (s < S_ - 1) {
      bool stm = (s >= starts[b] - 1) && (s <= ends[b] - 1);
      bool fam = (s >= ends[b]) && (s < rl[b] - 1);
      if (stm || fam) {
        float nll = logf(rowsum[i]) - tlog[i];
        if (stm) { st_s += nll; st_c += 1.f; }
        if (fam) { fa_s += nll; fa_c += 1.f; }
      }
    }
  }
  for (int i = tid; i < B_ * TM_; i += 256) {
    int row = MAIN_ROWS + i;
    float nll = logf(rowsum[row]) - tlog[row];
    float m = (float)mmask[i];
    m_s += nll * m; m_c += m;
  }
  float vals[6] = {st_s, st_c, fa_s, fa_c, m_s, m_c};
  for (int m = 1; m < 64; m <<= 1)
    for (int q = 0; q < 6; ++q) vals[q] += __shfl_xor(vals[q], m, 64);
  if ((tid & 63) == 0)
    for (int q = 0; q < 6; ++q) red[(tid >> 6) * 6 + q] = vals[q];
  __syncthreads();
  if (tid == 0) {
    float stS = red[0] + red[6] + red[12] + red[18];
    float stC = red[1] + red[7] + red[13] + red[19];
    float faS = red[2] + red[8] + red[14] + red[20];
    float faC = red[3] + red[9] + red[15] + red[21];
    float mS  = red[4] + red[10] + red[16] + red[22];
    float mC  = red[5] + red[11] + red[17] + red[23];
    float st = stS / fmaxf(stC, 1.f);
    float fa = faS / fmaxf(faC, 1.f);
    float ml = mS / fmaxf(mC, 1.f);
    out[0] = 0.5f * ml + 0.5f * st + 0.4f * fa;
    out[1] = ml;
    out[2] = st;
    out[3] = fa;
  }
}

extern "C" void kernel_launch(void* const* d_in, const int* in_sizes, int n_in,
                              void* d_out, int out_size, void* d_ws, size_t ws_size,
                              hipStream_t stream) {
  (void)in_sizes; (void)n_in; (void)out_size; (void)ws_size;
  const float* lhs      = (const float*)d_in[0];
  const int* input_ids  = (const int*)d_in[1];
  const int* attn       = (const int*)d_in[2];
  const int* starts     = (const int*)d_in[3];
  const int* ends       = (const int*)d_in[4];
  const int* mlabels    = (const int*)d_in[5];
  const int* mmask      = (const int*)d_in[6];
  const float* Am       = (const float*)d_in[8];
  const float* Bm       = (const float*)d_in[9];
  const float* bias     = (const float*)d_in[10];
  const float* Wf       = (const float*)d_in[11];
  float* out = (float*)d_out;

  char* ws = (char*)d_ws;
  unsigned char* Wq     = (unsigned char*)ws;                   // 65,536,000 B
  unsigned char* Xq     = (unsigned char*)(ws + 65536000);      // 12,582,912 B
  unsigned short* interb= (unsigned short*)(ws + 78118912);     //  1,048,576 B
  float* rowsum         = (float*)(ws + 79167488);              //     24,576 B
  float* tlog           = (float*)(ws + 79192064);              //     24,576 B

  hipMemsetAsync(rowsum, 0, MROWS * sizeof(float), stream);
  quant_fp8_k<<<(V_ * H_ / 16 + 255) / 256, 256, 0, stream>>>(Wf, (int*)Wq, WSCALE, V_ * H_ / 16);
  quant_fp8_k<<<(MAIN_ROWS * H_ / 16 + 255) / 256, 256, 0, stream>>>(lhs, (int*)Xq, 1.0f, MAIN_ROWS * H_ / 16);
  adapter1_k<<<B_ * NSEG_, 256, 0, stream>>>(lhs, starts, Bm, interb);
  adapter2_k<<<B_ * NSEG_ * 8, 256, 0, stream>>>(interb, Am, bias, Xq);
  ce_gemm_k<<<dim3(MROWS / BM, V_ / BN), 256, 0, stream>>>(Xq, Wq, starts, rowsum);
  tlogit_k<<<MROWS, 256, 0, stream>>>(Xq, Wq, input_ids, mlabels, tlog);
  finalize_k<<<1, 256, 0, stream>>>(rowsum, tlog, attn, starts, ends, mmask, out);
}